// Round 6
// baseline (532.667 us; speedup 1.0000x reference)
//
#include <hip/hip_runtime.h>

#define NB 32
#define NL 512
#define ND 512
#define NH 1024
#define NE 8
#define NROWS (NB * NL)       // 16384
#define CW 2048               // C width = [U|V]

typedef __attribute__((ext_vector_type(8))) short bf16x8;
typedef __attribute__((ext_vector_type(4))) float f32x4;

__device__ __forceinline__ unsigned short f2bf(float f) {
    unsigned u = __float_as_uint(f);
    return (unsigned short)((u + 0x7fffu + ((u >> 16) & 1u)) >> 16);
}
__device__ __forceinline__ float bf2f(unsigned short b) {
    return __uint_as_float(((unsigned)b) << 16);
}
__device__ __forceinline__ unsigned pkhi(float a, float b) {
    return (unsigned)f2bf(a) | ((unsigned)f2bf(b) << 16);
}

// ---------- W prep: transpose + split, packed [ntg 0..127][kb 0..15][lane][jp] ----------
__global__ __launch_bounds__(256) void wprep(
    const float* __restrict__ Wt, const float* __restrict__ Ws,
    unsigned* __restrict__ bpack)
{
    __shared__ float tile[64][65];
    int bid = blockIdx.x;
    int mat = bid >> 7, rem = bid & 127;
    int kt0 = (rem >> 4) << 6;
    int nt0 = (rem & 15) << 6;
    const float* W = mat ? Ws : Wt;
    unsigned* Oh = bpack;
    unsigned* Ol = bpack + 524288u;
    int t = threadIdx.x;
    #pragma unroll
    for (int i = 0; i < 16; ++i) {
        int idx = t + 256 * i;
        int k = idx >> 6, n = idx & 63;
        tile[k][n] = W[(size_t)(kt0 + k) * NH + nt0 + n];
    }
    __syncthreads();
    #pragma unroll
    for (int i = 0; i < 8; ++i) {
        int idx = t + 256 * i;
        int jp = idx & 3, lane = (idx >> 2) & 63, kbr = (idx >> 8) & 1, ntr = (idx >> 9) & 3;
        int ncol = ntr * 16 + (lane & 15);
        int kcol = kbr * 32 + ((lane >> 4) << 3) + jp * 2;
        float w0 = tile[kcol][ncol], w1 = tile[kcol + 1][ncol];
        unsigned short h0 = f2bf(w0), h1 = f2bf(w1);
        unsigned short l0 = f2bf(w0 - bf2f(h0)), l1 = f2bf(w1 - bf2f(h1));
        int ntg = mat * 64 + (nt0 >> 4) + ntr;
        int kb = (kt0 >> 5) + kbr;
        unsigned offs = ((unsigned)(ntg * 16 + kb) * 64u + (unsigned)lane) * 4u + jp;
        Oh[offs] = (unsigned)h0 | ((unsigned)h1 << 16);
        Ol[offs] = (unsigned)l0 | ((unsigned)l1 << 16);
    }
}

// ---------- stage 1: C = x @ [Wt|Ws]  (bf16 out; exact tiles get lo residual) ----------
__global__ __launch_bounds__(256) void gemm_uv(
    const float* __restrict__ x, const unsigned* __restrict__ bpack,
    unsigned short* __restrict__ C, unsigned short* __restrict__ Clo)
{
    __shared__ union {
        struct { unsigned Ah[4 * 64 * 4]; unsigned Al[4 * 64 * 4]; } a;
        unsigned short cs[64][272];
    } sm;

    const int tid = threadIdx.x, lane = tid & 63, wave = tid >> 6;
    const int g = lane >> 4, c = lane & 15;

    int bid = blockIdx.x;
    int xcd = bid & 7, kk = bid >> 3;
    int mi = (kk >> 2) + ((xcd >> 1) << 6);
    int ni = (kk & 3) + ((xcd & 1) << 2);
    const bool exact = (mi & 7) == 0;
    const int m0 = mi * 64;

    const unsigned* Bhi = bpack;
    const unsigned* Blo = bpack + 524288u;

    f32x4 acc[4][4];
    #pragma unroll
    for (int nf = 0; nf < 4; ++nf)
        #pragma unroll
        for (int mf = 0; mf < 4; ++mf) acc[nf][mf] = (f32x4){0.f, 0.f, 0.f, 0.f};

    const int rA = tid >> 3, cA = tid & 7;
    const int rB = (tid + 256) >> 3;

    auto ldx4 = [&](int kb, int row, int c4) -> float4 {
        return *(const float4*)&x[(size_t)(m0 + row) * ND + kb * 32 + c4 * 4];
    };
    auto cvw = [&](float4 v, int row, int c4) {
        int base = ((row >> 4) * 64 + (c4 >> 1) * 16 + (row & 15)) * 4 + (c4 & 1) * 2;
        if (exact) {
            unsigned short h0 = f2bf(v.x), h1 = f2bf(v.y), h2 = f2bf(v.z), h3 = f2bf(v.w);
            sm.a.Ah[base]     = (unsigned)h0 | ((unsigned)h1 << 16);
            sm.a.Ah[base + 1] = (unsigned)h2 | ((unsigned)h3 << 16);
            sm.a.Al[base]     = pkhi(v.x - bf2f(h0), v.y - bf2f(h1));
            sm.a.Al[base + 1] = pkhi(v.z - bf2f(h2), v.w - bf2f(h3));
        } else {
            sm.a.Ah[base]     = pkhi(v.x, v.y);
            sm.a.Ah[base + 1] = pkhi(v.z, v.w);
        }
    };

    float4 xa = ldx4(0, rA, cA), xb = ldx4(0, rB, cA);

    for (int kb = 0; kb < 16; ++kb) {
        __syncthreads();
        cvw(xa, rA, cA);
        cvw(xb, rB, cA);
        int kn = kb + 1 < 16 ? kb + 1 : 15;
        xa = ldx4(kn, rA, cA);
        xb = ldx4(kn, rB, cA);
        __syncthreads();

        const int nterm = exact ? 3 : 1;
        for (int t = 0; t < nterm; ++t) {
            const unsigned* As = (t == 1) ? sm.a.Al : sm.a.Ah;
            const unsigned* Bs = (t == 2) ? Blo : Bhi;
            bf16x8 af[4], bfr[4];
            #pragma unroll
            for (int mf = 0; mf < 4; ++mf)
                af[mf] = *(const bf16x8*)(As + (mf * 64 + lane) * 4);
            #pragma unroll
            for (int nf = 0; nf < 4; ++nf) {
                int nt = ni * 16 + wave * 4 + nf;
                bfr[nf] = *(const bf16x8*)(Bs + ((unsigned)(nt * 16 + kb) * 64u + (unsigned)lane) * 4u);
            }
            #pragma unroll
            for (int nf = 0; nf < 4; ++nf)
                #pragma unroll
                for (int mf = 0; mf < 4; ++mf)
                    acc[nf][mf] = __builtin_amdgcn_mfma_f32_16x16x32_bf16(af[mf], bfr[nf], acc[nf][mf], 0, 0, 0);
        }
    }

    __syncthreads();
    #pragma unroll
    for (int nf = 0; nf < 4; ++nf)
        #pragma unroll
        for (int mf = 0; mf < 4; ++mf)
            #pragma unroll
            for (int r = 0; r < 4; ++r)
                sm.cs[mf * 16 + g * 4 + r][wave * 64 + nf * 16 + c] = f2bf(acc[nf][mf][r]);
    __syncthreads();
    #pragma unroll
    for (int i = 0; i < 8; ++i) {
        int idx = tid + 256 * i;
        int row = idx >> 5, cg = idx & 31;
        *(uint4*)&C[(size_t)(m0 + row) * CW + ni * 256 + cg * 8] = *(const uint4*)&sm.cs[row][cg * 8];
    }
    if (exact) {
        __syncthreads();
        #pragma unroll
        for (int nf = 0; nf < 4; ++nf)
            #pragma unroll
            for (int mf = 0; mf < 4; ++mf)
                #pragma unroll
                for (int r = 0; r < 4; ++r) {
                    float v = acc[nf][mf][r];
                    sm.cs[mf * 16 + g * 4 + r][wave * 64 + nf * 16 + c] = f2bf(v - bf2f(f2bf(v)));
                }
        __syncthreads();
        int bq = mi >> 3;
        #pragma unroll
        for (int i = 0; i < 3; ++i) {
            int idx = tid + 256 * i;
            int row = idx >> 5, cg = idx & 31;
            if (row < 20)
                *(uint4*)&Clo[((size_t)bq * 20 + row) * CW + ni * 256 + cg * 8] = *(const uint4*)&sm.cs[row][cg * 8];
        }
    }
}

// ---------- stage 2a: LN stats partials (per col-quarter) ----------
// grid = b(32) x lc(8) x q(4); block 1024.  rowpart[row][q][2] = {sum, sumsq}
__global__ __launch_bounds__(1024) void stage2a(
    const unsigned short* __restrict__ C, const unsigned short* __restrict__ Clo,
    const float* __restrict__ bt, const float* __restrict__ bs,
    float* __restrict__ rowpart)
{
    __shared__ unsigned short stg[88][128];   // 22.5 KB
    __shared__ float exbuf[32][128];          // 16 KB
    __shared__ float statred[64][2][2];       //  1 KB

    const int tid = threadIdx.x;
    const int bid = blockIdx.x;
    const int q = bid & 3, lc = (bid >> 2) & 7, b = bid >> 5;
    const int l0 = lc * 64;
    const bool exact = (l0 == 0);
    const bool uv = q >= 2;

    const int cc = tid & 127, rg = tid >> 7;   // 8 row-groups x 128 cols
    float sum[8], sq[8];
    #pragma unroll
    for (int i = 0; i < 8; ++i) { sum[i] = 0.f; sq[i] = 0.f; }

    for (int ch = 0; ch < 4; ++ch) {
        int ccc = q * 512 + ch * 128;          // C col base
        __syncthreads();
        for (int i = tid; i < 88 * 128; i += 1024) {
            int si = i >> 7, c2 = i & 127;
            int l = l0 - 12 + si;
            l = l < 0 ? 0 : (l > NL - 1 ? NL - 1 : l);
            unsigned short h = C[(size_t)(b * NL + l) * CW + ccc + c2];
            stg[si][c2] = h;
            if (exact && si < 32)
                exbuf[si][c2] = bf2f(h) + bf2f(Clo[((size_t)b * 20 + l) * CW + ccc + c2]);
        }
        __syncthreads();

        float bias = uv ? bs[ccc + cc - 1024] : bt[ccc + cc];
        auto val = [&](int si) -> float {
            if (exact && si < 32) return exbuf[si][cc];
            return bf2f(stg[si][cc]);
        };
        int r0 = rg * 8;
        float run = 0.f;
        #pragma unroll
        for (int w = 0; w < 25; ++w) run += val(r0 + w);
        #pragma unroll
        for (int r = 0; r < 8; ++r) {
            if (r > 0) run += val(r0 + r + 24) - val(r0 + r - 1);
            float ma = run * (1.f / 25.f);
            float pre = uv ? (ma + bias) : (val(r0 + r + 12) - ma + bias);
            sum[r] += pre;
            sq[r] += pre * pre;
        }
    }

    // reduce across 128 cols: wave covers 64 cols; 2 waves per rg
    const int hhalf = (tid >> 6) & 1;
    #pragma unroll
    for (int r = 0; r < 8; ++r) {
        float s = sum[r], qq = sq[r];
        #pragma unroll
        for (int o = 1; o < 64; o <<= 1) { s += __shfl_xor(s, o); qq += __shfl_xor(qq, o); }
        if ((tid & 63) == 0) {
            statred[rg * 8 + r][hhalf][0] = s;
            statred[rg * 8 + r][hhalf][1] = qq;
        }
    }
    __syncthreads();
    if (tid < 64) {
        size_t gr = (size_t)b * NL + l0 + tid;
        rowpart[(gr * 4 + q) * 2 + 0] = statred[tid][0][0] + statred[tid][1][0];
        rowpart[(gr * 4 + q) * 2 + 1] = statred[tid][0][1] + statred[tid][1][1];
    }
}

// ---------- stage 3: MA + LN + med + W2 logit partials (per col-half) ----------
// grid = b(32) x lc(8) x half(2); block 1024.  lgpart[row][half][8]
__global__ __launch_bounds__(1024) void stage3(
    const unsigned short* __restrict__ C, const unsigned short* __restrict__ Clo,
    const float* __restrict__ bt, const float* __restrict__ gt, const float* __restrict__ bet,
    const float* __restrict__ bs, const float* __restrict__ gs, const float* __restrict__ bes,
    const float* __restrict__ W2, const float* __restrict__ rowpart,
    float* __restrict__ lgpart)
{
    __shared__ unsigned short stgU[88][64];   // 11.25 KB
    __shared__ unsigned short stgV[88][64];   // 11.25 KB
    __shared__ float exU[32][64];             //  8 KB
    __shared__ float exV[32][64];             //  8 KB
    __shared__ unsigned short medb[64][68];   //  8.7 KB
    __shared__ float exmed[8][68];            //  2.2 KB
    __shared__ float w2l[64][9];              //  2.3 KB
    __shared__ float rowstat[64][4];          //  1 KB

    const int tid = threadIdx.x;
    const int bid = blockIdx.x;
    const int half = bid & 1, lc = (bid >> 1) & 7, b = bid >> 4;
    const int l0 = lc * 64;
    const bool exact = (l0 == 0);

    // LN stats finalize for this block's 64 rows
    if (tid < 64) {
        size_t gr = (size_t)b * NL + l0 + tid;
        const float* p = &rowpart[gr * 8];
        float st = p[0] + p[2], qt = p[1] + p[3];
        float ss = p[4] + p[6], qs = p[5] + p[7];
        float mut = st * (1.f / NH), mus = ss * (1.f / NH);
        float vt = qt * (1.f / NH) - mut * mut;
        float vs = qs * (1.f / NH) - mus * mus;
        rowstat[tid][0] = mut; rowstat[tid][1] = rsqrtf(vt + 1e-5f);
        rowstat[tid][2] = mus; rowstat[tid][3] = rsqrtf(vs + 1e-5f);
    }

    float lg[NE];
    #pragma unroll
    for (int e = 0; e < NE; ++e) lg[e] = 0.f;

    for (int ch = 0; ch < 8; ++ch) {
        int hb = half * 512 + ch * 64;        // h col base (0..1023)
        __syncthreads();
        for (int i = tid; i < 88 * 64; i += 1024) {
            int si = i >> 6, c2 = i & 63;
            int l = l0 - 12 + si;
            l = l < 0 ? 0 : (l > NL - 1 ? NL - 1 : l);
            size_t rb = (size_t)(b * NL + l) * CW;
            unsigned short hu = C[rb + hb + c2];
            unsigned short hv = C[rb + NH + hb + c2];
            stgU[si][c2] = hu;
            stgV[si][c2] = hv;
            if (exact && si < 32) {
                size_t lb = ((size_t)b * 20 + l) * CW;
                exU[si][c2] = bf2f(hu) + bf2f(Clo[lb + hb + c2]);
                exV[si][c2] = bf2f(hv) + bf2f(Clo[lb + NH + hb + c2]);
            }
        }
        if (tid < 512) {
            int hh = tid >> 3, e = tid & 7;
            w2l[hh][e] = W2[(size_t)(hb + hh) * NE + e];
        }
        __syncthreads();

        {   // med compute: thread = (rg 0..15, cc 0..63), 4 rows each
            const int cc = tid & 63, rg = tid >> 6;
            const int r0 = rg * 4;
            int h = hb + cc;
            float btv = bt[h], bsv = bs[h];
            float gtv = gt[h], betv = bet[h], gsv = gs[h], besv = bes[h];
            auto vU = [&](int si) -> float {
                if (exact && si < 32) return exU[si][cc];
                return bf2f(stgU[si][cc]);
            };
            auto vV = [&](int si) -> float {
                if (exact && si < 32) return exV[si][cc];
                return bf2f(stgV[si][cc]);
            };
            float runU = 0.f, runV = 0.f;
            #pragma unroll
            for (int w = 0; w < 25; ++w) { runU += vU(r0 + w); runV += vV(r0 + w); }
            #pragma unroll
            for (int r = 0; r < 4; ++r) {
                if (r > 0) {
                    runU += vU(r0 + r + 24) - vU(r0 + r - 1);
                    runV += vV(r0 + r + 24) - vV(r0 + r - 1);
                }
                float maU = runU * (1.f / 25.f), maV = runV * (1.f / 25.f);
                float tpre = vU(r0 + r + 12) - maU + btv;
                float spre = maV + bsv;
                int row = r0 + r;
                float tn = (tpre - rowstat[row][0]) * rowstat[row][1] * gtv + betv;
                float sn = (spre - rowstat[row][2]) * rowstat[row][3] * gsv + besv;
                float m = tn + sn; m = m > 0.f ? m : 0.f;
                medb[row][cc] = f2bf(m);
                if (exact && row < 8) exmed[row][cc] = m;
            }
        }
        __syncthreads();

        {   // logits: thread = (row 0..63, cg 0..15), cols cg+16i
            const int row = tid >> 4, cg = tid & 15;
            #pragma unroll
            for (int i = 0; i < 4; ++i) {
                int col = cg + 16 * i;
                float m = (exact && row < 8) ? exmed[row][col] : bf2f(medb[row][col]);
                #pragma unroll
                for (int e = 0; e < NE; ++e) lg[e] = fmaf(m, w2l[col][e], lg[e]);
            }
        }
    }

    #pragma unroll
    for (int o = 1; o < 16; o <<= 1)
        #pragma unroll
        for (int e = 0; e < NE; ++e) lg[e] += __shfl_xor(lg[e], o);
    if ((tid & 15) == 0) {
        int row = tid >> 4;
        size_t gr = (size_t)b * NL + l0 + row;
        #pragma unroll
        for (int e = 0; e < NE; ++e)
            lgpart[(gr * 2 + half) * NE + e] = lg[e];
    }
}

// ---------- finalize2: per-row softmax/top2 -> mask bits + gates ----------
__global__ __launch_bounds__(256) void finalize2(
    const float* __restrict__ lgpart, const float* __restrict__ b2,
    unsigned* __restrict__ mb, float* __restrict__ gates)
{
    int row = blockIdx.x * 256 + threadIdx.x;
    if (row >= NROWS) return;
    int b = row >> 9, l = row & (NL - 1);
    float lg[NE];
    #pragma unroll
    for (int e = 0; e < NE; ++e)
        lg[e] = lgpart[(size_t)row * 2 * NE + e] + lgpart[((size_t)row * 2 + 1) * NE + e] + b2[e];
    float mx = lg[0];
    #pragma unroll
    for (int e = 1; e < NE; ++e) mx = lg[e] > mx ? lg[e] : mx;
    float p[NE]; float sum = 0.f;
    #pragma unroll
    for (int e = 0; e < NE; ++e) { p[e] = expf(lg[e] - mx); sum += p[e]; }
    float inv = 1.f / sum;
    int i0 = 0;
    #pragma unroll
    for (int e = 1; e < NE; ++e) if (lg[e] > lg[i0]) i0 = e;
    int i1 = i0 == 0 ? 1 : 0;
    #pragma unroll
    for (int e = 0; e < NE; ++e) if (e != i0 && lg[e] > lg[i1]) i1 = e;
    atomicOr(&mb[2 * b + 0], 1u << i0);
    atomicOr(&mb[2 * b + 1], 1u << i1);
    if (l < 8) {
        #pragma unroll
        for (int e = 0; e < NE; ++e)
            gates[((size_t)b * 8 + l) * NE + e] = p[e] * inv;
    }
}

// masked = gates * maskbit; denom = sum_b + 1e-4; out = masked/denom*64
__global__ void finalize_k(const unsigned* __restrict__ mb,
                           const float* __restrict__ gates,
                           float* __restrict__ out)
{
    int t = threadIdx.x;
    if (t >= 16) return;
    int l = t >> 1, e = t & 1;
    float m[NB];
    float sum = 0.f;
    #pragma unroll
    for (int bb = 0; bb < NB; ++bb) {
        float gvv = gates[((size_t)bb * 8 + l) * NE + e];
        float on  = ((mb[2 * bb + e] >> l) & 1u) ? 1.f : 0.f;
        m[bb] = gvv * on;
        sum += m[bb];
    }
    float scale = 64.f / (sum + 1e-4f);
    #pragma unroll
    for (int bb = 0; bb < NB; ++bb)
        out[(size_t)bb * (NL * NE) + l * NE + e] = m[bb] * scale;
}

extern "C" void kernel_launch(void* const* d_in, const int* in_sizes, int n_in,
                              void* d_out, int out_size, void* d_ws, size_t ws_size,
                              hipStream_t stream) {
    const float* x   = (const float*)d_in[0];
    const float* Wt  = (const float*)d_in[1];
    const float* bt  = (const float*)d_in[2];
    const float* gt  = (const float*)d_in[3];
    const float* bet = (const float*)d_in[4];
    const float* Ws  = (const float*)d_in[5];
    const float* bs  = (const float*)d_in[6];
    const float* gs  = (const float*)d_in[7];
    const float* bes = (const float*)d_in[8];
    const float* W2  = (const float*)d_in[9];
    const float* b2  = (const float*)d_in[10];
    float* out = (float*)d_out;

    char* wsb = (char*)d_ws;
    unsigned*       mbp   = (unsigned*)wsb;                            // 256 B
    float*          gates = (float*)(wsb + 256);                       // 2 KB
    unsigned*       bpack = (unsigned*)(wsb + 4096);                   // 4 MiB (dead after gemm_uv)
    float*          rowpart = (float*)(wsb + 4096);                    // 512 KB (aliases bpack)
    float*          lgpart  = (float*)(wsb + 4096 + 524288);           // 1 MB   (aliases bpack)
    unsigned short* C     = (unsigned short*)(wsb + 4096 + 4194304);   // 64 MiB
    unsigned short* Clo   = (unsigned short*)(wsb + 4096 + 4194304 + (size_t)NROWS * CW * 2);  // 2.5 MiB

    hipMemsetAsync(d_out, 0, sizeof(float) * NB * NL * NE, stream);
    hipMemsetAsync(mbp, 0, 256, stream);

    wprep<<<256, 256, 0, stream>>>(Wt, Ws, bpack);
    gemm_uv<<<2048, 256, 0, stream>>>(x, bpack, C, Clo);
    stage2a<<<1024, 1024, 0, stream>>>(C, Clo, bt, bs, rowpart);
    stage3<<<512, 1024, 0, stream>>>(C, Clo, bt, gt, bet, bs, gs, bes, W2, rowpart, lgpart);
    finalize2<<<64, 256, 0, stream>>>(lgpart, b2, mbp, gates);
    finalize_k<<<1, 64, 0, stream>>>(mbp, gates, out);
}

// Round 7
// 217.654 us; speedup vs baseline: 2.4473x; 2.4473x over previous
//
#include <hip/hip_runtime.h>

#define NB 32
#define NL 512
#define ND 512
#define NH 1024
#define NE 8
#define NROWS (NB * NL)       // 16384
#define CW 2048               // C width = [U|V]
#define SPAD 136              // LDS row pad: 272B stride, 16B-aligned

typedef __attribute__((ext_vector_type(8))) short bf16x8;
typedef __attribute__((ext_vector_type(4))) float f32x4;

__device__ __forceinline__ unsigned short f2bf(float f) {
    unsigned u = __float_as_uint(f);
    return (unsigned short)((u + 0x7fffu + ((u >> 16) & 1u)) >> 16);
}
__device__ __forceinline__ float bf2f(unsigned short b) {
    return __uint_as_float(((unsigned)b) << 16);
}
__device__ __forceinline__ unsigned pkhi(float a, float b) {
    return (unsigned)f2bf(a) | ((unsigned)f2bf(b) << 16);
}

// ---------- W prep: transpose + split, packed [ntg][kb][lane][jp] ----------
__global__ __launch_bounds__(256) void wprep(
    const float* __restrict__ Wt, const float* __restrict__ Ws,
    unsigned* __restrict__ bpack)
{
    __shared__ float tile[64][65];
    int bid = blockIdx.x;
    int mat = bid >> 7, rem = bid & 127;
    int kt0 = (rem >> 4) << 6;
    int nt0 = (rem & 15) << 6;
    const float* W = mat ? Ws : Wt;
    unsigned* Oh = bpack;
    unsigned* Ol = bpack + 524288u;
    int t = threadIdx.x;
    #pragma unroll
    for (int i = 0; i < 16; ++i) {
        int idx = t + 256 * i;
        int k = idx >> 6, n = idx & 63;
        tile[k][n] = W[(size_t)(kt0 + k) * NH + nt0 + n];
    }
    __syncthreads();
    #pragma unroll
    for (int i = 0; i < 8; ++i) {
        int idx = t + 256 * i;
        int jp = idx & 3, lane = (idx >> 2) & 63, kbr = (idx >> 8) & 1, ntr = (idx >> 9) & 3;
        int ncol = ntr * 16 + (lane & 15);
        int kcol = kbr * 32 + ((lane >> 4) << 3) + jp * 2;
        float w0 = tile[kcol][ncol], w1 = tile[kcol + 1][ncol];
        unsigned short h0 = f2bf(w0), h1 = f2bf(w1);
        unsigned short l0 = f2bf(w0 - bf2f(h0)), l1 = f2bf(w1 - bf2f(h1));
        int ntg = mat * 64 + (nt0 >> 4) + ntr;
        int kb = (kt0 >> 5) + kbr;
        unsigned offs = ((unsigned)(ntg * 16 + kb) * 64u + (unsigned)lane) * 4u + jp;
        Oh[offs] = (unsigned)h0 | ((unsigned)h1 << 16);
        Ol[offs] = (unsigned)l0 | ((unsigned)l1 << 16);
    }
}

// ---------- stage 1: C = x @ [Wt|Ws] (bf16; row<20 tiles get lo residual) ----------
__global__ __launch_bounds__(256) void gemm_uv(
    const float* __restrict__ x, const unsigned* __restrict__ bpack,
    unsigned short* __restrict__ C, unsigned short* __restrict__ Clo)
{
    __shared__ union {
        struct { unsigned Ah[4 * 64 * 4]; unsigned Al[4 * 64 * 4]; } a;
        unsigned short cs[64][272];
    } sm;

    const int tid = threadIdx.x, lane = tid & 63, wave = tid >> 6;
    const int g = lane >> 4, c = lane & 15;

    int bid = blockIdx.x;
    int xcd = bid & 7, kk = bid >> 3;
    int mi = (kk >> 2) + ((xcd >> 1) << 6);
    int ni = (kk & 3) + ((xcd & 1) << 2);
    const bool exact = (mi & 7) == 0;
    const int m0 = mi * 64;

    const unsigned* Bhi = bpack;
    const unsigned* Blo = bpack + 524288u;

    f32x4 acc[4][4];
    #pragma unroll
    for (int nf = 0; nf < 4; ++nf)
        #pragma unroll
        for (int mf = 0; mf < 4; ++mf) acc[nf][mf] = (f32x4){0.f, 0.f, 0.f, 0.f};

    const int rA = tid >> 3, cA = tid & 7;
    const int rB = (tid + 256) >> 3;

    auto ldx4 = [&](int kb, int row, int c4) -> float4 {
        return *(const float4*)&x[(size_t)(m0 + row) * ND + kb * 32 + c4 * 4];
    };
    auto cvw = [&](float4 v, int row, int c4) {
        int base = ((row >> 4) * 64 + (c4 >> 1) * 16 + (row & 15)) * 4 + (c4 & 1) * 2;
        if (exact) {
            unsigned short h0 = f2bf(v.x), h1 = f2bf(v.y), h2 = f2bf(v.z), h3 = f2bf(v.w);
            sm.a.Ah[base]     = (unsigned)h0 | ((unsigned)h1 << 16);
            sm.a.Ah[base + 1] = (unsigned)h2 | ((unsigned)h3 << 16);
            sm.a.Al[base]     = pkhi(v.x - bf2f(h0), v.y - bf2f(h1));
            sm.a.Al[base + 1] = pkhi(v.z - bf2f(h2), v.w - bf2f(h3));
        } else {
            sm.a.Ah[base]     = pkhi(v.x, v.y);
            sm.a.Ah[base + 1] = pkhi(v.z, v.w);
        }
    };

    float4 xa = ldx4(0, rA, cA), xb = ldx4(0, rB, cA);

    for (int kb = 0; kb < 16; ++kb) {
        __syncthreads();
        cvw(xa, rA, cA);
        cvw(xb, rB, cA);
        int kn = kb + 1 < 16 ? kb + 1 : 15;
        xa = ldx4(kn, rA, cA);
        xb = ldx4(kn, rB, cA);
        __syncthreads();

        const int nterm = exact ? 3 : 1;
        for (int t = 0; t < nterm; ++t) {
            const unsigned* As = (t == 1) ? sm.a.Al : sm.a.Ah;
            const unsigned* Bs = (t == 2) ? Blo : Bhi;
            bf16x8 af[4], bfr[4];
            #pragma unroll
            for (int mf = 0; mf < 4; ++mf)
                af[mf] = *(const bf16x8*)(As + (mf * 64 + lane) * 4);
            #pragma unroll
            for (int nf = 0; nf < 4; ++nf) {
                int nt = ni * 16 + wave * 4 + nf;
                bfr[nf] = *(const bf16x8*)(Bs + ((unsigned)(nt * 16 + kb) * 64u + (unsigned)lane) * 4u);
            }
            #pragma unroll
            for (int nf = 0; nf < 4; ++nf)
                #pragma unroll
                for (int mf = 0; mf < 4; ++mf)
                    acc[nf][mf] = __builtin_amdgcn_mfma_f32_16x16x32_bf16(af[mf], bfr[nf], acc[nf][mf], 0, 0, 0);
        }
    }

    __syncthreads();
    #pragma unroll
    for (int nf = 0; nf < 4; ++nf)
        #pragma unroll
        for (int mf = 0; mf < 4; ++mf)
            #pragma unroll
            for (int r = 0; r < 4; ++r)
                sm.cs[mf * 16 + g * 4 + r][wave * 64 + nf * 16 + c] = f2bf(acc[nf][mf][r]);
    __syncthreads();
    #pragma unroll
    for (int i = 0; i < 8; ++i) {
        int idx = tid + 256 * i;
        int row = idx >> 5, cg = idx & 31;
        *(uint4*)&C[(size_t)(m0 + row) * CW + ni * 256 + cg * 8] = *(const uint4*)&sm.cs[row][cg * 8];
    }
    if (exact) {
        __syncthreads();
        #pragma unroll
        for (int nf = 0; nf < 4; ++nf)
            #pragma unroll
            for (int mf = 0; mf < 4; ++mf)
                #pragma unroll
                for (int r = 0; r < 4; ++r) {
                    float v = acc[nf][mf][r];
                    sm.cs[mf * 16 + g * 4 + r][wave * 64 + nf * 16 + c] = f2bf(v - bf2f(f2bf(v)));
                }
        __syncthreads();
        int bq = mi >> 3;
        #pragma unroll
        for (int i = 0; i < 3; ++i) {
            int idx = tid + 256 * i;
            int row = idx >> 5, cg = idx & 31;
            if (row < 20)
                *(uint4*)&Clo[((size_t)bq * 20 + row) * CW + ni * 256 + cg * 8] = *(const uint4*)&sm.cs[row][cg * 8];
        }
    }
}

// ---------- stats_k: LN stat partials, pure bf16, vectorized ----------
// grid = b(32) x lc(8) x q(4); block 256; q = col quarter of CW (0,1=U; 2,3=V)
__global__ __launch_bounds__(256) void stats_k(
    const unsigned short* __restrict__ C,
    const float* __restrict__ bt, const float* __restrict__ bs,
    float* __restrict__ rowpart)
{
    __shared__ unsigned short stg[88][SPAD];

    const int tid = threadIdx.x;
    const int bid = blockIdx.x;
    const int q = bid & 3, lc = (bid >> 2) & 7, b = bid >> 5;
    const int l0 = lc * 64;
    const int cq = tid & 31, rg = tid >> 5;
    const float inv25 = 1.f / 25.f;

    float s[8], qa[8];
    #pragma unroll
    for (int r = 0; r < 8; ++r) { s[r] = 0.f; qa[r] = 0.f; }

    for (int ch = 0; ch < 4; ++ch) {
        int cb = q * 512 + ch * 128;
        __syncthreads();
        for (int i = tid; i < 1408; i += 256) {
            int si = i >> 4, cg = i & 15;
            int gl = l0 - 12 + si;
            gl = gl < 0 ? 0 : (gl > NL - 1 ? NL - 1 : gl);
            *(uint4*)&stg[si][cg * 8] = *(const uint4*)&C[(size_t)(b * NL + gl) * CW + cb + cg * 8];
        }
        __syncthreads();

        float bv[4];
        {
            float4 b4 = q < 2 ? *(const float4*)&bt[cb + cq * 4]
                              : *(const float4*)&bs[cb - 1024 + cq * 4];
            bv[0] = b4.x; bv[1] = b4.y; bv[2] = b4.z; bv[3] = b4.w;
        }
        float run[4] = {0.f, 0.f, 0.f, 0.f};
        #pragma unroll
        for (int w = 0; w < 25; ++w) {
            ushort4 u = *(const ushort4*)&stg[rg * 8 + w][cq * 4];
            run[0] += bf2f(u.x); run[1] += bf2f(u.y); run[2] += bf2f(u.z); run[3] += bf2f(u.w);
        }
        #pragma unroll
        for (int rr = 0; rr < 8; ++rr) {
            if (rr > 0) {
                ushort4 un = *(const ushort4*)&stg[rg * 8 + rr + 24][cq * 4];
                ushort4 uo = *(const ushort4*)&stg[rg * 8 + rr - 1][cq * 4];
                run[0] += bf2f(un.x) - bf2f(uo.x); run[1] += bf2f(un.y) - bf2f(uo.y);
                run[2] += bf2f(un.z) - bf2f(uo.z); run[3] += bf2f(un.w) - bf2f(uo.w);
            }
            float pre[4];
            if (q < 2) {
                ushort4 uc = *(const ushort4*)&stg[rg * 8 + rr + 12][cq * 4];
                pre[0] = bf2f(uc.x) - run[0] * inv25 + bv[0];
                pre[1] = bf2f(uc.y) - run[1] * inv25 + bv[1];
                pre[2] = bf2f(uc.z) - run[2] * inv25 + bv[2];
                pre[3] = bf2f(uc.w) - run[3] * inv25 + bv[3];
            } else {
                pre[0] = run[0] * inv25 + bv[0];
                pre[1] = run[1] * inv25 + bv[1];
                pre[2] = run[2] * inv25 + bv[2];
                pre[3] = run[3] * inv25 + bv[3];
            }
            s[rr]  += pre[0] + pre[1] + pre[2] + pre[3];
            qa[rr] += pre[0] * pre[0] + pre[1] * pre[1] + pre[2] * pre[2] + pre[3] * pre[3];
        }
    }

    #pragma unroll
    for (int rr = 0; rr < 8; ++rr)
        #pragma unroll
        for (int o = 1; o < 32; o <<= 1) {
            s[rr]  += __shfl_xor(s[rr], o);
            qa[rr] += __shfl_xor(qa[rr], o);
        }
    if (cq == 0) {
        #pragma unroll
        for (int rr = 0; rr < 8; ++rr) {
            size_t gr = (size_t)b * NL + l0 + rg * 8 + rr;
            rowpart[(gr * 4 + q) * 2 + 0] = s[rr];
            rowpart[(gr * 4 + q) * 2 + 1] = qa[rr];
        }
    }
}

// ---------- apply_k: MA+LN+med+logits+top2+mask OR (bf16; skips rows l<8 OR) ----------
// grid = b(32) x lc(8); block 256
__global__ __launch_bounds__(256) void apply_k(
    const unsigned short* __restrict__ C,
    const float* __restrict__ bt, const float* __restrict__ gt, const float* __restrict__ bet,
    const float* __restrict__ bs, const float* __restrict__ gs, const float* __restrict__ bes,
    const float* __restrict__ W2, const float* __restrict__ b2,
    const float* __restrict__ rowpart, unsigned* __restrict__ mb)
{
    __shared__ unsigned short stgU[88][SPAD];
    __shared__ unsigned short stgV[88][SPAD];
    __shared__ float4 rowstat[64];
    __shared__ float lgf[64][NE];

    const int tid = threadIdx.x;
    const int bid = blockIdx.x;
    const int lc = bid & 7, b = bid >> 3;
    const int l0 = lc * 64;
    const int cq = tid & 31, rg = tid >> 5;
    const float inv25 = 1.f / 25.f;

    if (tid < 64) {
        size_t gr = (size_t)b * NL + l0 + tid;
        const float* p = &rowpart[gr * 8];
        float st = p[0] + p[2], qt = p[1] + p[3];
        float ss = p[4] + p[6], qs = p[5] + p[7];
        float mut = st * (1.f / NH), mus = ss * (1.f / NH);
        float vt = qt * (1.f / NH) - mut * mut;
        float vs = qs * (1.f / NH) - mus * mus;
        rowstat[tid] = make_float4(mut, rsqrtf(vt + 1e-5f), mus, rsqrtf(vs + 1e-5f));
    }
    __syncthreads();

    float lgp[8][NE];
    #pragma unroll
    for (int r = 0; r < 8; ++r)
        #pragma unroll
        for (int e = 0; e < NE; ++e) lgp[r][e] = 0.f;

    for (int ch = 0; ch < 8; ++ch) {
        int hb = ch * 128;
        __syncthreads();
        for (int i = tid; i < 1408; i += 256) {
            int si = i >> 4, cg = i & 15;
            int gl = l0 - 12 + si;
            gl = gl < 0 ? 0 : (gl > NL - 1 ? NL - 1 : gl);
            size_t rb = (size_t)(b * NL + gl) * CW;
            *(uint4*)&stgU[si][cg * 8] = *(const uint4*)&C[rb + hb + cg * 8];
            *(uint4*)&stgV[si][cg * 8] = *(const uint4*)&C[rb + NH + hb + cg * 8];
        }
        __syncthreads();

        int col = hb + cq * 4;
        float4 btv = *(const float4*)&bt[col],  gtv = *(const float4*)&gt[col];
        float4 bev = *(const float4*)&bet[col], bsv = *(const float4*)&bs[col];
        float4 gsv = *(const float4*)&gs[col],  besv = *(const float4*)&bes[col];
        float btr[4] = {btv.x, btv.y, btv.z, btv.w};
        float gtr[4] = {gtv.x, gtv.y, gtv.z, gtv.w};
        float ber[4] = {bev.x, bev.y, bev.z, bev.w};
        float bsr[4] = {bsv.x, bsv.y, bsv.z, bsv.w};
        float gsr[4] = {gsv.x, gsv.y, gsv.z, gsv.w};
        float besr[4] = {besv.x, besv.y, besv.z, besv.w};
        float w2r[4][NE];
        #pragma unroll
        for (int j = 0; j < 4; ++j) {
            const float4* wp = (const float4*)&W2[(size_t)(col + j) * NE];
            float4 a = wp[0], c2 = wp[1];
            w2r[j][0] = a.x;  w2r[j][1] = a.y;  w2r[j][2] = a.z;  w2r[j][3] = a.w;
            w2r[j][4] = c2.x; w2r[j][5] = c2.y; w2r[j][6] = c2.z; w2r[j][7] = c2.w;
        }

        float runU[4] = {0.f, 0.f, 0.f, 0.f}, runV[4] = {0.f, 0.f, 0.f, 0.f};
        #pragma unroll
        for (int w = 0; w < 25; ++w) {
            ushort4 u = *(const ushort4*)&stgU[rg * 8 + w][cq * 4];
            ushort4 v = *(const ushort4*)&stgV[rg * 8 + w][cq * 4];
            runU[0] += bf2f(u.x); runU[1] += bf2f(u.y); runU[2] += bf2f(u.z); runU[3] += bf2f(u.w);
            runV[0] += bf2f(v.x); runV[1] += bf2f(v.y); runV[2] += bf2f(v.z); runV[3] += bf2f(v.w);
        }
        #pragma unroll
        for (int rr = 0; rr < 8; ++rr) {
            if (rr > 0) {
                ushort4 un = *(const ushort4*)&stgU[rg * 8 + rr + 24][cq * 4];
                ushort4 uo = *(const ushort4*)&stgU[rg * 8 + rr - 1][cq * 4];
                ushort4 vn = *(const ushort4*)&stgV[rg * 8 + rr + 24][cq * 4];
                ushort4 vo = *(const ushort4*)&stgV[rg * 8 + rr - 1][cq * 4];
                runU[0] += bf2f(un.x) - bf2f(uo.x); runU[1] += bf2f(un.y) - bf2f(uo.y);
                runU[2] += bf2f(un.z) - bf2f(uo.z); runU[3] += bf2f(un.w) - bf2f(uo.w);
                runV[0] += bf2f(vn.x) - bf2f(vo.x); runV[1] += bf2f(vn.y) - bf2f(vo.y);
                runV[2] += bf2f(vn.z) - bf2f(vo.z); runV[3] += bf2f(vn.w) - bf2f(vo.w);
            }
            float4 rs = rowstat[rg * 8 + rr];
            ushort4 uc = *(const ushort4*)&stgU[rg * 8 + rr + 12][cq * 4];
            float cen[4] = {bf2f(uc.x), bf2f(uc.y), bf2f(uc.z), bf2f(uc.w)};
            float med[4];
            #pragma unroll
            for (int j = 0; j < 4; ++j) {
                float tn = ((cen[j] - runU[j] * inv25 + btr[j]) - rs.x) * rs.y * gtr[j] + ber[j];
                float sn = ((runV[j] * inv25 + bsr[j]) - rs.z) * rs.w * gsr[j] + besr[j];
                float m = tn + sn;
                med[j] = m > 0.f ? m : 0.f;
            }
            #pragma unroll
            for (int e = 0; e < NE; ++e)
                lgp[rr][e] = fmaf(med[0], w2r[0][e], fmaf(med[1], w2r[1][e],
                             fmaf(med[2], w2r[2][e], fmaf(med[3], w2r[3][e], lgp[rr][e]))));
        }
    }

    #pragma unroll
    for (int rr = 0; rr < 8; ++rr)
        #pragma unroll
        for (int e = 0; e < NE; ++e)
            #pragma unroll
            for (int o = 1; o < 32; o <<= 1)
                lgp[rr][e] += __shfl_xor(lgp[rr][e], o);
    if (cq == 0)
        #pragma unroll
        for (int rr = 0; rr < 8; ++rr)
            #pragma unroll
            for (int e = 0; e < NE; ++e) lgf[rg * 8 + rr][e] = lgp[rr][e];
    __syncthreads();

    if (tid < 64) {
        float lg[NE];
        #pragma unroll
        for (int e = 0; e < NE; ++e) lg[e] = lgf[tid][e] + b2[e];
        int i0 = 0;
        #pragma unroll
        for (int e = 1; e < NE; ++e) if (lg[e] > lg[i0]) i0 = e;
        int i1 = i0 == 0 ? 1 : 0;
        #pragma unroll
        for (int e = 0; e < NE; ++e) if (e != i0 && lg[e] > lg[i1]) i1 = e;
        bool skip = (lc == 0 && tid < 8);   // exact_k owns rows l<8
        unsigned m = skip ? 0u : ((1u << i0) | (1u << (8 + i1)));
        #pragma unroll
        for (int o = 1; o < 64; o <<= 1) m |= __shfl_xor(m, o);
        if (tid == 0) {
            atomicOr(&mb[2 * b + 0], m & 0xffu);
            atomicOr(&mb[2 * b + 1], m >> 8);
        }
    }
}

// ---------- exact_k: exact gates + mask bits for rows l<8 (per batch) ----------
// grid = 32; block 256; thread owns 4 adjacent h-cols
__global__ __launch_bounds__(256) void exact_k(
    const unsigned short* __restrict__ C, const unsigned short* __restrict__ Clo,
    const float* __restrict__ bt, const float* __restrict__ gt, const float* __restrict__ bet,
    const float* __restrict__ bs, const float* __restrict__ gs, const float* __restrict__ bes,
    const float* __restrict__ W2, const float* __restrict__ b2,
    unsigned* __restrict__ mb, float* __restrict__ gates)
{
    __shared__ float statred[4][8][4];
    __shared__ float rowstatx[8][4];
    __shared__ float lgred[4][8][NE];

    const int tid = threadIdx.x;
    const int b = blockIdx.x;
    const int h0 = tid * 4;
    const int wv = tid >> 6;
    const float inv25 = 1.f / 25.f;

    float4 btv = *(const float4*)&bt[h0],  gtv = *(const float4*)&gt[h0];
    float4 bev = *(const float4*)&bet[h0], bsv = *(const float4*)&bs[h0];
    float4 gsv = *(const float4*)&gs[h0],  besv = *(const float4*)&bes[h0];

    auto exv = [&](int j, int off, float* o4) {
        ushort4 h = *(const ushort4*)&C[(size_t)(b * NL + j) * CW + off + h0];
        ushort4 l = *(const ushort4*)&Clo[((size_t)b * 20 + j) * CW + off + h0];
        o4[0] = bf2f(h.x) + bf2f(l.x); o4[1] = bf2f(h.y) + bf2f(l.y);
        o4[2] = bf2f(h.z) + bf2f(l.z); o4[3] = bf2f(h.w) + bf2f(l.w);
    };

    // ---- pass 1: exact LN stats for rows l<8 ----
    float st[8], qt[8], ss[8], qs[8];
    #pragma unroll
    for (int r = 0; r < 8; ++r) { st[r] = 0.f; qt[r] = 0.f; ss[r] = 0.f; qs[r] = 0.f; }
    {
        float csU[4] = {0,0,0,0}, csV[4] = {0,0,0,0}, v0U[4], v0V[4];
        #pragma unroll
        for (int j = 0; j < 20; ++j) {
            float u[4], v[4];
            exv(j, 0, u); exv(j, NH, v);
            if (j == 0) {
                #pragma unroll
                for (int k = 0; k < 4; ++k) { v0U[k] = u[k]; v0V[k] = v[k]; }
            }
            #pragma unroll
            for (int k = 0; k < 4; ++k) { csU[k] += u[k]; csV[k] += v[k]; }
            if (j >= 12) {
                const int l = j - 12;
                const float w0 = (float)(24 - j);   // 12 - l
                float ul[4];
                exv(l, 0, ul);
                float btr[4] = {btv.x, btv.y, btv.z, btv.w};
                float bsr[4] = {bsv.x, bsv.y, bsv.z, bsv.w};
                #pragma unroll
                for (int k = 0; k < 4; ++k) {
                    float maU = (csU[k] + w0 * v0U[k]) * inv25;
                    float maV = (csV[k] + w0 * v0V[k]) * inv25;
                    float pt = ul[k] - maU + btr[k];
                    float ps = maV + bsr[k];
                    st[l] += pt; qt[l] += pt * pt;
                    ss[l] += ps; qs[l] += ps * ps;
                }
            }
        }
    }
    #pragma unroll
    for (int r = 0; r < 8; ++r)
        #pragma unroll
        for (int o = 1; o < 64; o <<= 1) {
            st[r] += __shfl_xor(st[r], o); qt[r] += __shfl_xor(qt[r], o);
            ss[r] += __shfl_xor(ss[r], o); qs[r] += __shfl_xor(qs[r], o);
        }
    if ((tid & 63) == 0)
        #pragma unroll
        for (int r = 0; r < 8; ++r) {
            statred[wv][r][0] = st[r]; statred[wv][r][1] = qt[r];
            statred[wv][r][2] = ss[r]; statred[wv][r][3] = qs[r];
        }
    __syncthreads();
    if (tid < 8) {
        float a0 = 0, a1 = 0, a2 = 0, a3 = 0;
        #pragma unroll
        for (int w = 0; w < 4; ++w) {
            a0 += statred[w][tid][0]; a1 += statred[w][tid][1];
            a2 += statred[w][tid][2]; a3 += statred[w][tid][3];
        }
        float mut = a0 * (1.f / NH), mus = a2 * (1.f / NH);
        float vt = a1 * (1.f / NH) - mut * mut;
        float vs = a3 * (1.f / NH) - mus * mus;
        rowstatx[tid][0] = mut; rowstatx[tid][1] = rsqrtf(vt + 1e-5f);
        rowstatx[tid][2] = mus; rowstatx[tid][3] = rsqrtf(vs + 1e-5f);
    }
    __syncthreads();

    // ---- pass 2: exact med + logits ----
    float w2r[4][NE];
    #pragma unroll
    for (int j = 0; j < 4; ++j) {
        const float4* wp = (const float4*)&W2[(size_t)(h0 + j) * NE];
        float4 a = wp[0], c2 = wp[1];
        w2r[j][0] = a.x;  w2r[j][1] = a.y;  w2r[j][2] = a.z;  w2r[j][3] = a.w;
        w2r[j][4] = c2.x; w2r[j][5] = c2.y; w2r[j][6] = c2.z; w2r[j][7] = c2.w;
    }
    float lgp[8][NE];
    #pragma unroll
    for (int r = 0; r < 8; ++r)
        #pragma unroll
        for (int e = 0; e < NE; ++e) lgp[r][e] = 0.f;
    {
        float csU[4] = {0,0,0,0}, csV[4] = {0,0,0,0}, v0U[4], v0V[4];
        #pragma unroll
        for (int j = 0; j < 20; ++j) {
            float u[4], v[4];
            exv(j, 0, u); exv(j, NH, v);
            if (j == 0) {
                #pragma unroll
                for (int k = 0; k < 4; ++k) { v0U[k] = u[k]; v0V[k] = v[k]; }
            }
            #pragma unroll
            for (int k = 0; k < 4; ++k) { csU[k] += u[k]; csV[k] += v[k]; }
            if (j >= 12) {
                const int l = j - 12;
                const float w0 = (float)(24 - j);
                float ul[4];
                exv(l, 0, ul);
                float btr[4] = {btv.x, btv.y, btv.z, btv.w};
                float bsr[4] = {bsv.x, bsv.y, bsv.z, bsv.w};
                float gtr[4] = {gtv.x, gtv.y, gtv.z, gtv.w};
                float ber[4] = {bev.x, bev.y, bev.z, bev.w};
                float gsr[4] = {gsv.x, gsv.y, gsv.z, gsv.w};
                float besr[4] = {besv.x, besv.y, besv.z, besv.w};
                float mu_t = rowstatx[l][0], rs_t = rowstatx[l][1];
                float mu_s = rowstatx[l][2], rs_s = rowstatx[l][3];
                float med[4];
                #pragma unroll
                for (int k = 0; k < 4; ++k) {
                    float maU = (csU[k] + w0 * v0U[k]) * inv25;
                    float maV = (csV[k] + w0 * v0V[k]) * inv25;
                    float tn = ((ul[k] - maU + btr[k]) - mu_t) * rs_t * gtr[k] + ber[k];
                    float sn = ((maV + bsr[k]) - mu_s) * rs_s * gsr[k] + besr[k];
                    float m = tn + sn;
                    med[k] = m > 0.f ? m : 0.f;
                }
                #pragma unroll
                for (int e = 0; e < NE; ++e)
                    lgp[l][e] = fmaf(med[0], w2r[0][e], fmaf(med[1], w2r[1][e],
                                fmaf(med[2], w2r[2][e], fmaf(med[3], w2r[3][e], lgp[l][e]))));
            }
        }
    }
    #pragma unroll
    for (int r = 0; r < 8; ++r)
        #pragma unroll
        for (int e = 0; e < NE; ++e)
            #pragma unroll
            for (int o = 1; o < 64; o <<= 1)
                lgp[r][e] += __shfl_xor(lgp[r][e], o);
    if ((tid & 63) == 0)
        #pragma unroll
        for (int r = 0; r < 8; ++r)
            #pragma unroll
            for (int e = 0; e < NE; ++e) lgred[wv][r][e] = lgp[r][e];
    __syncthreads();

    if (tid < 8) {
        float lg[NE];
        #pragma unroll
        for (int e = 0; e < NE; ++e)
            lg[e] = lgred[0][tid][e] + lgred[1][tid][e] + lgred[2][tid][e] + lgred[3][tid][e] + b2[e];
        float mx = lg[0];
        #pragma unroll
        for (int e = 1; e < NE; ++e) mx = lg[e] > mx ? lg[e] : mx;
        float p[NE]; float sum = 0.f;
        #pragma unroll
        for (int e = 0; e < NE; ++e) { p[e] = expf(lg[e] - mx); sum += p[e]; }
        float inv = 1.f / sum;
        int i0 = 0;
        #pragma unroll
        for (int e = 1; e < NE; ++e) if (lg[e] > lg[i0]) i0 = e;
        int i1 = i0 == 0 ? 1 : 0;
        #pragma unroll
        for (int e = 0; e < NE; ++e) if (e != i0 && lg[e] > lg[i1]) i1 = e;
        atomicOr(&mb[2 * b + 0], 1u << i0);
        atomicOr(&mb[2 * b + 1], 1u << i1);
        #pragma unroll
        for (int e = 0; e < NE; ++e)
            gates[((size_t)b * 8 + tid) * NE + e] = p[e] * inv;
    }
}

// masked = gates * maskbit; denom = sum_b + 1e-4; out = masked/denom*64
__global__ void finalize_k(const unsigned* __restrict__ mb,
                           const float* __restrict__ gates,
                           float* __restrict__ out)
{
    int t = threadIdx.x;
    if (t >= 16) return;
    int l = t >> 1, e = t & 1;
    float m[NB];
    float sum = 0.f;
    #pragma unroll
    for (int bb = 0; bb < NB; ++bb) {
        float gvv = gates[((size_t)bb * 8 + l) * NE + e];
        float on  = ((mb[2 * bb + e] >> l) & 1u) ? 1.f : 0.f;
        m[bb] = gvv * on;
        sum += m[bb];
    }
    float scale = 64.f / (sum + 1e-4f);
    #pragma unroll
    for (int bb = 0; bb < NB; ++bb)
        out[(size_t)bb * (NL * NE) + l * NE + e] = m[bb] * scale;
}

extern "C" void kernel_launch(void* const* d_in, const int* in_sizes, int n_in,
                              void* d_out, int out_size, void* d_ws, size_t ws_size,
                              hipStream_t stream) {
    const float* x   = (const float*)d_in[0];
    const float* Wt  = (const float*)d_in[1];
    const float* bt  = (const float*)d_in[2];
    const float* gt  = (const float*)d_in[3];
    const float* bet = (const float*)d_in[4];
    const float* Ws  = (const float*)d_in[5];
    const float* bs  = (const float*)d_in[6];
    const float* gs  = (const float*)d_in[7];
    const float* bes = (const float*)d_in[8];
    const float* W2  = (const float*)d_in[9];
    const float* b2  = (const float*)d_in[10];
    float* out = (float*)d_out;

    char* wsb = (char*)d_ws;
    unsigned*       mbp   = (unsigned*)wsb;                            // 256 B
    float*          gates = (float*)(wsb + 256);                       // 2 KB
    unsigned*       bpack = (unsigned*)(wsb + 4096);                   // 4 MiB (dead after gemm_uv)
    float*          rowpart = (float*)(wsb + 4096);                    // 512 KB (aliases bpack)
    unsigned short* C     = (unsigned short*)(wsb + 4096 + 4194304);   // 64 MiB
    unsigned short* Clo   = (unsigned short*)(wsb + 4096 + 4194304 + (size_t)NROWS * CW * 2);  // 2.5 MiB

    hipMemsetAsync(d_out, 0, sizeof(float) * NB * NL * NE, stream);
    hipMemsetAsync(mbp, 0, 256, stream);

    wprep<<<256, 256, 0, stream>>>(Wt, Ws, bpack);
    gemm_uv<<<2048, 256, 0, stream>>>(x, bpack, C, Clo);
    stats_k<<<1024, 256, 0, stream>>>(C, bt, bs, rowpart);
    apply_k<<<256, 256, 0, stream>>>(C, bt, gt, bet, bs, gs, bes, W2, b2, rowpart, mbp);
    exact_k<<<32, 256, 0, stream>>>(C, Clo, bt, gt, bet, bs, gs, bes, W2, b2, mbp, gates);
    finalize_k<<<1, 64, 0, stream>>>(mbp, gates, out);
}